// Round 2
// baseline (1270.694 us; speedup 1.0000x reference)
//
#include <hip/hip_runtime.h>
#include <stdint.h>

typedef unsigned short u16;
typedef unsigned int u32;
typedef __attribute__((ext_vector_type(4))) float f32x4;
typedef __attribute__((ext_vector_type(8))) short bf16x8;

#define NN 32768
#define EE 524288
#define DD 384
#define NREL 8
#define NGR 128
#define KREL (NREL * DD)  // 3072
#define LN2 (2 * DD)      // 768

__device__ __forceinline__ float bf2f(u16 u) {
  union { u32 u; float f; } v; v.u = ((u32)u) << 16; return v.f;
}
__device__ __forceinline__ u16 f2bf(float f) {
  union { float f; u32 u; } v; v.f = f;
  u32 r = v.u + 0x7fffu + ((v.u >> 16) & 1u);
  return (u16)(r >> 16);
}
__device__ __forceinline__ float2 up2(u32 p) {
  return make_float2(bf2f((u16)(p & 0xffffu)), bf2f((u16)(p >> 16)));
}
__device__ __forceinline__ u32 pk2(float a, float b) {
  return (u32)f2bf(a) | ((u32)f2bf(b) << 16);
}

// ---- per-node inverse norm + x -> bf16 ; also zeroes cur[] ----
__global__ __launch_bounds__(256) void k_invnorm(const float* __restrict__ x,
                                                 float* __restrict__ invn,
                                                 u16* __restrict__ h0,
                                                 int* __restrict__ cur) {
  const int gid = blockIdx.x * 256 + threadIdx.x;
  if (gid < NN) cur[gid] = 0;
  const int node = gid >> 6;
  const int l = threadIdx.x & 63;
  const float* row = x + (size_t)node * DD;
  float v[6];
  float s = 0.f;
#pragma unroll
  for (int j = 0; j < 6; ++j) { v[j] = row[l + 64 * j]; s += v[j] * v[j]; }
#pragma unroll
  for (int off = 32; off > 0; off >>= 1) s += __shfl_xor(s, off, 64);
  if (l == 0) invn[node] = rsqrtf(s);
  u16* hr = h0 + (size_t)node * DD;
#pragma unroll
  for (int j = 0; j < 6; ++j) hr[l + 64 * j] = f2bf(v[j]);
}

// ---- weight transpose + bf16 convert ----
// WcatT[n][k] (384 x 3072) = W_rel flat[k*384 + n]
// WmsT[j][k]  (768 x 384)  = j<384 ? W_mp[k][j] : W_self[k][j-384]
__global__ void k_prepW(const float* __restrict__ Wrel, const float* __restrict__ Wmp,
                        const float* __restrict__ Wself,
                        u16* __restrict__ WcatT, u16* __restrict__ WmsT) {
  const int i = blockIdx.x * 256 + threadIdx.x;
  const int total1 = DD * KREL;
  const int total2 = LN2 * DD;
  if (i < total1) {
    const int n = i / KREL, k = i % KREL;
    WcatT[i] = f2bf(Wrel[(size_t)k * DD + n]);
  } else if (i < total1 + total2) {
    const int ii = i - total1;
    const int j = ii / DD, k = ii % DD;
    const float v = (j < DD) ? Wmp[k * DD + j] : Wself[k * DD + (j - DD)];
    WmsT[ii] = f2bf(v);
  }
}

// ---- per-edge weight w_e = cos(x_src, x_dst) / norm_constants[type] ----
__global__ __launch_bounds__(256) void k_cos(const float* __restrict__ x,
                                             const float* __restrict__ invn,
                                             const int* __restrict__ ei,
                                             const int* __restrict__ etype,
                                             const float* __restrict__ ncs,
                                             float* __restrict__ we) {
  const int e = (int)((blockIdx.x * 256 + threadIdx.x) >> 6);
  const int l = threadIdx.x & 63;
  const int s = ei[e], d = ei[EE + e];
  const float* rs = x + (size_t)s * DD;
  const float* rd = x + (size_t)d * DD;
  float acc = 0.f;
#pragma unroll
  for (int j = 0; j < 6; ++j) acc += rs[l + 64 * j] * rd[l + 64 * j];
#pragma unroll
  for (int off = 32; off > 0; off >>= 1) acc += __shfl_xor(acc, off, 64);
  if (l == 0) we[e] = acc * invn[s] * invn[d] / ncs[etype[e]];
}

__global__ void k_hist(const int* __restrict__ ei, int* __restrict__ cnt) {
  const int e = blockIdx.x * 256 + threadIdx.x;
  atomicAdd(&cnt[ei[EE + e]], 1);
}

// single block, 1024 threads: exclusive scan of 32768 degrees
__global__ __launch_bounds__(1024) void k_scan(const int* __restrict__ deg,
                                               int* __restrict__ rp,
                                               int* __restrict__ cur) {
  __shared__ int ps[1024];
  const int t = threadIdx.x;
  const int base = t * 32;
  int loc[32];
  int tot = 0;
#pragma unroll
  for (int j = 0; j < 32; ++j) { loc[j] = tot; tot += deg[base + j]; }
  ps[t] = tot;
  __syncthreads();
  for (int off = 1; off < 1024; off <<= 1) {
    const int v = (t >= off) ? ps[t - off] : 0;
    __syncthreads();
    ps[t] += v;
    __syncthreads();
  }
  const int myoff = ps[t] - tot;  // exclusive
#pragma unroll
  for (int j = 0; j < 32; ++j) {
    const int val = myoff + loc[j];
    rp[base + j] = val;
    cur[base + j] = val;
  }
  if (t == 1023) rp[NN] = EE;
}

__global__ void k_scatter(const int* __restrict__ ei, const int* __restrict__ etype,
                          const float* __restrict__ we, int* __restrict__ cur,
                          int* __restrict__ epack, float* __restrict__ wsort) {
  const int e = blockIdx.x * 256 + threadIdx.x;
  const int d = ei[EE + e];
  const int pos = atomicAdd(&cur[d], 1);
  epack[pos] = ei[e] | (etype[e] << 16);
  wsort[pos] = we[e];
}

// ---- relation-aware aggregation for nodes [base, base+gridDim) ----
// agg[blockIdx][r*384+d] = sum_{e->i, type r} w_e * h[src][d]; also sbuf[i][r] = sum w
__global__ __launch_bounds__(192) void k_edge_rel(
    const u16* __restrict__ H, const int* __restrict__ rp,
    const int* __restrict__ epack, const float* __restrict__ wsort,
    u16* __restrict__ agg, float* __restrict__ sbuf, int base) {
  const int i = base + blockIdx.x;
  const int t = threadIdx.x;
  const int e0 = rp[i], e1 = rp[i + 1];
  float2 a0 = {0, 0}, a1 = {0, 0}, a2 = {0, 0}, a3 = {0, 0};
  float2 a4 = {0, 0}, a5 = {0, 0}, a6 = {0, 0}, a7 = {0, 0};
  float s0 = 0, s1 = 0, s2 = 0, s3 = 0, s4 = 0, s5 = 0, s6 = 0, s7 = 0;
  for (int e = e0; e < e1; ++e) {
    const int pk = epack[e];
    const float w = wsort[e];
    const int src = pk & 0xffff;
    const int ty = pk >> 16;
    const float2 hv = up2(*(const u32*)(H + (size_t)src * DD + 2 * t));
    const float vx = w * hv.x, vy = w * hv.y;
    switch (ty) {
      case 0: a0.x += vx; a0.y += vy; if (t == 0) s0 += w; break;
      case 1: a1.x += vx; a1.y += vy; if (t == 0) s1 += w; break;
      case 2: a2.x += vx; a2.y += vy; if (t == 0) s2 += w; break;
      case 3: a3.x += vx; a3.y += vy; if (t == 0) s3 += w; break;
      case 4: a4.x += vx; a4.y += vy; if (t == 0) s4 += w; break;
      case 5: a5.x += vx; a5.y += vy; if (t == 0) s5 += w; break;
      case 6: a6.x += vx; a6.y += vy; if (t == 0) s6 += w; break;
      default: a7.x += vx; a7.y += vy; if (t == 0) s7 += w; break;
    }
  }
  u32* ap = (u32*)(agg + (size_t)blockIdx.x * KREL);
  ap[0 * 192 + t] = pk2(a0.x, a0.y);
  ap[1 * 192 + t] = pk2(a1.x, a1.y);
  ap[2 * 192 + t] = pk2(a2.x, a2.y);
  ap[3 * 192 + t] = pk2(a3.x, a3.y);
  ap[4 * 192 + t] = pk2(a4.x, a4.y);
  ap[5 * 192 + t] = pk2(a5.x, a5.y);
  ap[6 * 192 + t] = pk2(a6.x, a6.y);
  ap[7 * 192 + t] = pk2(a7.x, a7.y);
  if (t == 0) {
    float* sp = sbuf + (size_t)i * 8;
    sp[0] = s0; sp[1] = s1; sp[2] = s2; sp[3] = s3;
    sp[4] = s4; sp[5] = s5; sp[6] = s6; sp[7] = s7;
  }
}

// ---- bf16 MFMA GEMM, C = A[M,K] @ Bt[N,K]^T, 128x128 tile, BK=32, 4 waves ----
// mode 0: o[row*os+col] = bf16(relu(C + s @ b_rel))   (N=384, os=384)
// mode 1: o[row*os+col] = bf16(C + (col<384 ? b_mp[col] : b_self[col-384])) (N=768, os=768)
__global__ __launch_bounds__(256) void k_gemm(
    const u16* __restrict__ A, const u16* __restrict__ Bt, int K, int mode,
    u16* __restrict__ o_bf, int ostride,
    const float* __restrict__ sbuf, const float* __restrict__ brel,
    const float* __restrict__ bmp, const float* __restrict__ bself) {
  __shared__ __align__(16) u16 As[128 * 32];
  __shared__ __align__(16) u16 Bs[128 * 32];
  const int tid = threadIdx.x;
  const int nb = blockIdx.x * 128;
  const int mb = blockIdx.y * 128;
  const int w = tid >> 6, l = tid & 63;
  const int wr = (w >> 1) * 64;
  const int wc = (w & 1) * 64;
  const int sr = tid >> 2;
  const int sc = (tid & 3) * 8;
  const int lr = l & 15;
  const int lk = (l >> 4) * 8;
  f32x4 acc[4][4] = {};
  const size_t arow0 = (size_t)(mb + sr) * K;
  const size_t arow1 = (size_t)(mb + sr + 64) * K;
  const size_t brow0 = (size_t)(nb + sr) * K;
  const size_t brow1 = (size_t)(nb + sr + 64) * K;
  for (int k0 = 0; k0 < K; k0 += 32) {
    *(int4*)(As + sr * 32 + sc)        = *(const int4*)(A + arow0 + k0 + sc);
    *(int4*)(As + (sr + 64) * 32 + sc) = *(const int4*)(A + arow1 + k0 + sc);
    *(int4*)(Bs + sr * 32 + sc)        = *(const int4*)(Bt + brow0 + k0 + sc);
    *(int4*)(Bs + (sr + 64) * 32 + sc) = *(const int4*)(Bt + brow1 + k0 + sc);
    __syncthreads();
    bf16x8 af[4], bfr[4];
#pragma unroll
    for (int m = 0; m < 4; ++m)
      af[m] = *(const bf16x8*)(As + (wr + m * 16 + lr) * 32 + lk);
#pragma unroll
    for (int n = 0; n < 4; ++n)
      bfr[n] = *(const bf16x8*)(Bs + (wc + n * 16 + lr) * 32 + lk);
#pragma unroll
    for (int m = 0; m < 4; ++m)
#pragma unroll
      for (int n = 0; n < 4; ++n)
        acc[m][n] = __builtin_amdgcn_mfma_f32_16x16x32_bf16(af[m], bfr[n], acc[m][n], 0, 0, 0);
    __syncthreads();
  }
  const int lg = l >> 4;
#pragma unroll
  for (int n = 0; n < 4; ++n) {
    const int col = nb + wc + n * 16 + lr;
    float bcol[8];
    if (mode == 0) {
#pragma unroll
      for (int r = 0; r < 8; ++r) bcol[r] = brel[r * DD + col];
    }
    float bb = 0.f;
    if (mode == 1) bb = (col < DD) ? bmp[col] : bself[col - DD];
#pragma unroll
    for (int m = 0; m < 4; ++m) {
#pragma unroll
      for (int q = 0; q < 4; ++q) {
        const int row = mb + wr + m * 16 + lg * 4 + q;
        float v = acc[m][n][q];
        if (mode == 0) {
          const float* sp = sbuf + (size_t)row * 8;
          float bias = 0.f;
#pragma unroll
          for (int r = 0; r < 8; ++r) bias += sp[r] * bcol[r];
          v = fmaxf(v + bias, 0.f);
        } else {
          v += bb;
        }
        o_bf[(size_t)row * ostride + col] = f2bf(v);
      }
    }
  }
}

// ---- MP aggregation + self + relu: H[i] = relu(sum_e lin2[src][0:384] + lin2[i][384:768]) ----
__global__ __launch_bounds__(192) void k_edge_mp(
    const u16* __restrict__ lin2, const int* __restrict__ rp,
    const int* __restrict__ epack, u16* __restrict__ Hout) {
  const int i = blockIdx.x, t = threadIdx.x;
  const int e0 = rp[i], e1 = rp[i + 1];
  float ax = 0.f, ay = 0.f;
  for (int e = e0; e < e1; ++e) {
    const int src = epack[e] & 0xffff;
    const float2 hv = up2(*(const u32*)(lin2 + (size_t)src * LN2 + 2 * t));
    ax += hv.x; ay += hv.y;
  }
  const float2 sl = up2(*(const u32*)(lin2 + (size_t)i * LN2 + DD + 2 * t));
  ax = fmaxf(ax + sl.x, 0.f);
  ay = fmaxf(ay + sl.y, 0.f);
  *(u32*)(Hout + (size_t)i * DD + 2 * t) = pk2(ax, ay);
}

// ---- mean over 256 nodes per graph ----
__global__ __launch_bounds__(192) void k_mean(const u16* __restrict__ H,
                                              float* __restrict__ out) {
  const int g = blockIdx.x, t = threadIdx.x;
  float ax = 0.f, ay = 0.f;
  const u16* base = H + (size_t)g * 256 * DD;
  for (int j = 0; j < 256; ++j) {
    const float2 hv = up2(*(const u32*)(base + (size_t)j * DD + 2 * t));
    ax += hv.x; ay += hv.y;
  }
  out[g * DD + 2 * t]     = ax * (1.f / 256.f);
  out[g * DD + 2 * t + 1] = ay * (1.f / 256.f);
}

extern "C" void kernel_launch(void* const* d_in, const int* in_sizes, int n_in,
                              void* d_out, int out_size, void* d_ws, size_t ws_size,
                              hipStream_t stream) {
  const float* x     = (const float*)d_in[0];
  const int*   ei    = (const int*)d_in[1];
  const int*   ety   = (const int*)d_in[2];
  const float* Wrel  = (const float*)d_in[4];
  const float* brel  = (const float*)d_in[5];
  const float* ncs   = (const float*)d_in[6];
  const float* Wmp   = (const float*)d_in[7];
  const float* bmp   = (const float*)d_in[8];
  const float* Wself = (const float*)d_in[9];
  const float* bself = (const float*)d_in[10];
  float* out = (float*)d_out;
  (void)in_sizes; (void)n_in; (void)out_size;

  char* ws = (char*)d_ws;
  size_t off = 0;
  auto alloc = [&](size_t bytes) {
    void* p = ws + off;
    off = (off + bytes + 255) & ~(size_t)255;
    return p;
  };
  float* invn  = (float*)alloc((size_t)NN * 4);
  int*   rp    = (int*)alloc(((size_t)NN + 1) * 4);
  int*   cur   = (int*)alloc((size_t)NN * 4);
  float* sbuf  = (float*)alloc((size_t)NN * 8 * 4);
  float* we    = (float*)alloc((size_t)EE * 4);
  int*   epack = (int*)alloc((size_t)EE * 4);
  float* wsort = (float*)alloc((size_t)EE * 4);
  u16*   WcatT = (u16*)alloc((size_t)DD * KREL * 2);
  u16*   WmsT  = (u16*)alloc((size_t)LN2 * DD * 2);
  u16*   H     = (u16*)alloc((size_t)NN * DD * 2);
  u16*   H2    = (u16*)alloc((size_t)NN * DD * 2);
  u16*   lin2  = (u16*)alloc((size_t)NN * LN2 * 2);
  // adaptive agg chunk: largest C (power-of-two fraction of NN, >=1024) that fits
  size_t remain = (ws_size > off) ? (ws_size - off) : 0;
  int C = NN;
  while (C > 1024 && (size_t)C * KREL * 2 > remain) C >>= 1;
  u16* agg = (u16*)(ws + off);

  k_invnorm<<<NN / 4, 256, 0, stream>>>(x, invn, H, cur);
  k_prepW<<<(DD * KREL + LN2 * DD) / 256, 256, 0, stream>>>(Wrel, Wmp, Wself, WcatT, WmsT);
  k_cos<<<EE / 4, 256, 0, stream>>>(x, invn, ei, ety, ncs, we);
  k_hist<<<EE / 256, 256, 0, stream>>>(ei, cur);
  k_scan<<<1, 1024, 0, stream>>>(cur, rp, cur);
  k_scatter<<<EE / 256, 256, 0, stream>>>(ei, ety, we, cur, epack, wsort);

  for (int layer = 0; layer < 2; ++layer) {
    for (int c0 = 0; c0 < NN; c0 += C) {
      k_edge_rel<<<C, 192, 0, stream>>>(H, rp, epack, wsort, agg, sbuf, c0);
      k_gemm<<<dim3(3, C / 128), 256, 0, stream>>>(agg, WcatT, KREL, 0,
                                                   H2 + (size_t)c0 * DD, DD,
                                                   sbuf + (size_t)c0 * 8, brel, nullptr, nullptr);
    }
    k_gemm<<<dim3(6, NN / 128), 256, 0, stream>>>(H2, WmsT, DD, 1,
                                                  lin2, LN2, nullptr, nullptr, bmp, bself);
    k_edge_mp<<<NN, 192, 0, stream>>>(lin2, rp, epack, H);
  }
  k_mean<<<NGR, 192, 0, stream>>>(H, out);
}

// Round 3
// 1159.284 us; speedup vs baseline: 1.0961x; 1.0961x over previous
//
#include <hip/hip_runtime.h>
#include <stdint.h>

typedef unsigned short u16;
typedef unsigned int u32;
typedef __attribute__((ext_vector_type(4))) float f32x4;
typedef __attribute__((ext_vector_type(8))) short bf16x8;

#define NN 32768
#define EE 524288
#define DD 384
#define NREL 8
#define NGR 128
#define KREL (NREL * DD)  // 3072
#define LN2 (2 * DD)      // 768

__device__ __forceinline__ float bf2f(u16 u) {
  union { u32 u; float f; } v; v.u = ((u32)u) << 16; return v.f;
}
__device__ __forceinline__ u16 f2bf(float f) {
  union { float f; u32 u; } v; v.f = f;
  u32 r = v.u + 0x7fffu + ((v.u >> 16) & 1u);
  return (u16)(r >> 16);
}
__device__ __forceinline__ float2 up2(u32 p) {
  return make_float2(bf2f((u16)(p & 0xffffu)), bf2f((u16)(p >> 16)));
}
__device__ __forceinline__ u32 pk2(float a, float b) {
  return (u32)f2bf(a) | ((u32)f2bf(b) << 16);
}
// async 16B global->LDS (one dwordx4 per lane; LDS dest = wave base + lane*16)
__device__ __forceinline__ void gl16(const u16* g, char* s) {
  __builtin_amdgcn_global_load_lds(
      (const __attribute__((address_space(1))) unsigned int*)(const void*)g,
      (__attribute__((address_space(3))) unsigned int*)(void*)s, 16, 0, 0);
}

// ---- per-node inverse norm + x -> bf16 ; also zeroes cur[] ----
__global__ __launch_bounds__(256) void k_invnorm(const float* __restrict__ x,
                                                 float* __restrict__ invn,
                                                 u16* __restrict__ h0,
                                                 int* __restrict__ cur) {
  const int gid = blockIdx.x * 256 + threadIdx.x;
  if (gid < NN) cur[gid] = 0;
  const int node = gid >> 6;
  const int l = threadIdx.x & 63;
  const float* row = x + (size_t)node * DD;
  float v[6];
  float s = 0.f;
#pragma unroll
  for (int j = 0; j < 6; ++j) { v[j] = row[l + 64 * j]; s += v[j] * v[j]; }
#pragma unroll
  for (int off = 32; off > 0; off >>= 1) s += __shfl_xor(s, off, 64);
  if (l == 0) invn[node] = rsqrtf(s);
  u16* hr = h0 + (size_t)node * DD;
#pragma unroll
  for (int j = 0; j < 6; ++j) hr[l + 64 * j] = f2bf(v[j]);
}

// ---- weight transpose + bf16 convert ----
__global__ void k_prepW(const float* __restrict__ Wrel, const float* __restrict__ Wmp,
                        const float* __restrict__ Wself,
                        u16* __restrict__ WcatT, u16* __restrict__ WmsT) {
  const int i = blockIdx.x * 256 + threadIdx.x;
  const int total1 = DD * KREL;
  const int total2 = LN2 * DD;
  if (i < total1) {
    const int n = i / KREL, k = i % KREL;
    WcatT[i] = f2bf(Wrel[(size_t)k * DD + n]);
  } else if (i < total1 + total2) {
    const int ii = i - total1;
    const int j = ii / DD, k = ii % DD;
    const float v = (j < DD) ? Wmp[k * DD + j] : Wself[k * DD + (j - DD)];
    WmsT[ii] = f2bf(v);
  }
}

// ---- per-edge weight w_e = cos(x_src, x_dst)/ncs[type], bf16 rows, fused hist ----
__global__ __launch_bounds__(256) void k_cos(const u16* __restrict__ Hb,
                                             const float* __restrict__ invn,
                                             const int* __restrict__ ei,
                                             const int* __restrict__ etype,
                                             const float* __restrict__ ncs,
                                             float* __restrict__ we,
                                             int* __restrict__ cnt) {
  const int e = (int)((blockIdx.x * 256 + threadIdx.x) >> 6);
  const int l = threadIdx.x & 63;
  const int s = ei[e], d = ei[EE + e];
  const u32* rs = (const u32*)(Hb + (size_t)s * DD);
  const u32* rd = (const u32*)(Hb + (size_t)d * DD);
  float acc = 0.f;
#pragma unroll
  for (int j = 0; j < 3; ++j) {
    const float2 a = up2(rs[l + 64 * j]);
    const float2 b = up2(rd[l + 64 * j]);
    acc += a.x * b.x + a.y * b.y;
  }
#pragma unroll
  for (int off = 32; off > 0; off >>= 1) acc += __shfl_xor(acc, off, 64);
  if (l == 0) {
    we[e] = acc * invn[s] * invn[d] / ncs[etype[e]];
    atomicAdd(&cnt[d], 1);
  }
}

// single block, 1024 threads: exclusive scan of 32768 degrees
__global__ __launch_bounds__(1024) void k_scan(const int* __restrict__ deg,
                                               int* __restrict__ rp,
                                               int* __restrict__ cur) {
  __shared__ int ps[1024];
  const int t = threadIdx.x;
  const int base = t * 32;
  int loc[32];
  int tot = 0;
#pragma unroll
  for (int j = 0; j < 32; ++j) { loc[j] = tot; tot += deg[base + j]; }
  ps[t] = tot;
  __syncthreads();
  for (int off = 1; off < 1024; off <<= 1) {
    const int v = (t >= off) ? ps[t - off] : 0;
    __syncthreads();
    ps[t] += v;
    __syncthreads();
  }
  const int myoff = ps[t] - tot;  // exclusive
#pragma unroll
  for (int j = 0; j < 32; ++j) {
    const int val = myoff + loc[j];
    rp[base + j] = val;
    cur[base + j] = val;
  }
  if (t == 1023) rp[NN] = EE;
}

__global__ void k_scatter(const int* __restrict__ ei, const int* __restrict__ etype,
                          const float* __restrict__ we, int* __restrict__ cur,
                          int* __restrict__ epack, float* __restrict__ wsort) {
  const int e = blockIdx.x * 256 + threadIdx.x;
  const int d = ei[EE + e];
  const int pos = atomicAdd(&cur[d], 1);
  epack[pos] = ei[e] | (etype[e] << 16);
  wsort[pos] = we[e];
}

// ---- relation-aware aggregation for nodes [base, base+gridDim) ----
__global__ __launch_bounds__(192) void k_edge_rel(
    const u16* __restrict__ H, const int* __restrict__ rp,
    const int* __restrict__ epack, const float* __restrict__ wsort,
    u16* __restrict__ agg, float* __restrict__ sbuf, int base) {
  const int i = base + blockIdx.x;
  const int t = threadIdx.x;
  const int e0 = rp[i], e1 = rp[i + 1];
  float2 a0 = {0, 0}, a1 = {0, 0}, a2 = {0, 0}, a3 = {0, 0};
  float2 a4 = {0, 0}, a5 = {0, 0}, a6 = {0, 0}, a7 = {0, 0};
  float s0 = 0, s1 = 0, s2 = 0, s3 = 0, s4 = 0, s5 = 0, s6 = 0, s7 = 0;
  for (int e = e0; e < e1; ++e) {
    const int pk = epack[e];
    const float w = wsort[e];
    const int src = pk & 0xffff;
    const int ty = pk >> 16;
    const float2 hv = up2(*(const u32*)(H + (size_t)src * DD + 2 * t));
    const float vx = w * hv.x, vy = w * hv.y;
    switch (ty) {
      case 0: a0.x += vx; a0.y += vy; if (t == 0) s0 += w; break;
      case 1: a1.x += vx; a1.y += vy; if (t == 0) s1 += w; break;
      case 2: a2.x += vx; a2.y += vy; if (t == 0) s2 += w; break;
      case 3: a3.x += vx; a3.y += vy; if (t == 0) s3 += w; break;
      case 4: a4.x += vx; a4.y += vy; if (t == 0) s4 += w; break;
      case 5: a5.x += vx; a5.y += vy; if (t == 0) s5 += w; break;
      case 6: a6.x += vx; a6.y += vy; if (t == 0) s6 += w; break;
      default: a7.x += vx; a7.y += vy; if (t == 0) s7 += w; break;
    }
  }
  u32* ap = (u32*)(agg + (size_t)blockIdx.x * KREL);
  ap[0 * 192 + t] = pk2(a0.x, a0.y);
  ap[1 * 192 + t] = pk2(a1.x, a1.y);
  ap[2 * 192 + t] = pk2(a2.x, a2.y);
  ap[3 * 192 + t] = pk2(a3.x, a3.y);
  ap[4 * 192 + t] = pk2(a4.x, a4.y);
  ap[5 * 192 + t] = pk2(a5.x, a5.y);
  ap[6 * 192 + t] = pk2(a6.x, a6.y);
  ap[7 * 192 + t] = pk2(a7.x, a7.y);
  if (t == 0) {
    float* sp = sbuf + (size_t)i * 8;
    sp[0] = s0; sp[1] = s1; sp[2] = s2; sp[3] = s3;
    sp[4] = s4; sp[5] = s5; sp[6] = s6; sp[7] = s7;
  }
}

// ---- bf16 MFMA GEMM, C = A[M,K] @ Bt[N,K]^T, 128x128 tile, BK=64, 4 waves ----
// staging via global_load_lds width=16 (m97 structure)
// mode 0: o = bf16(relu(C + s @ b_rel))   (N=384)
// mode 1: o = bf16(C + (col<384 ? b_mp[col] : b_self[col-384])) (N=768)
__global__ __launch_bounds__(256) void k_gemm(
    const u16* __restrict__ A, const u16* __restrict__ Bt, int K, int mode,
    u16* __restrict__ o_bf, int ostride,
    const float* __restrict__ sbuf, const float* __restrict__ brel,
    const float* __restrict__ bmp, const float* __restrict__ bself) {
  __shared__ __align__(16) u16 As[128 * 64];
  __shared__ __align__(16) u16 Bs[128 * 64];
  const int tid = threadIdx.x;
  const int nb = blockIdx.x * 128;
  const int mb = blockIdx.y * 128;
  const int w = tid >> 6, l = tid & 63;
  const int wr = (w >> 1) * 64;
  const int wc = (w & 1) * 64;
  const int sr = tid >> 3;        // 0..31 (row within 32-row segment)
  const int sc = (tid & 7) * 8;   // u16 col within BK=64
  const int lr = l & 15;
  const int lk = (l >> 4) * 8;
  char* asb = (char*)As;
  char* bsb = (char*)Bs;
  const int wb = w * 1024;        // wave-linear LDS byte base
  f32x4 acc[4][4] = {};
  const u16* a0 = A + (size_t)(mb + sr) * K + sc;
  const u16* b0 = Bt + (size_t)(nb + sr) * K + sc;
  const size_t r32 = (size_t)32 * K;
  for (int k0 = 0; k0 < K; k0 += 64) {
    gl16(a0 + k0,           asb + wb);
    gl16(a0 + k0 + r32,     asb + wb + 4096);
    gl16(a0 + k0 + 2 * r32, asb + wb + 8192);
    gl16(a0 + k0 + 3 * r32, asb + wb + 12288);
    gl16(b0 + k0,           bsb + wb);
    gl16(b0 + k0 + r32,     bsb + wb + 4096);
    gl16(b0 + k0 + 2 * r32, bsb + wb + 8192);
    gl16(b0 + k0 + 3 * r32, bsb + wb + 12288);
    __syncthreads();
#pragma unroll
    for (int kk = 0; kk < 64; kk += 32) {
      bf16x8 af[4], bfr[4];
#pragma unroll
      for (int m = 0; m < 4; ++m)
        af[m] = *(const bf16x8*)(As + (wr + m * 16 + lr) * 64 + kk + lk);
#pragma unroll
      for (int n = 0; n < 4; ++n)
        bfr[n] = *(const bf16x8*)(Bs + (wc + n * 16 + lr) * 64 + kk + lk);
#pragma unroll
      for (int m = 0; m < 4; ++m)
#pragma unroll
        for (int n = 0; n < 4; ++n)
          acc[m][n] = __builtin_amdgcn_mfma_f32_16x16x32_bf16(af[m], bfr[n], acc[m][n], 0, 0, 0);
    }
    __syncthreads();
  }
  const int lg = l >> 4;
#pragma unroll
  for (int n = 0; n < 4; ++n) {
    const int col = nb + wc + n * 16 + lr;
    float bcol[8];
    if (mode == 0) {
#pragma unroll
      for (int r = 0; r < 8; ++r) bcol[r] = brel[r * DD + col];
    }
    float bb = 0.f;
    if (mode == 1) bb = (col < DD) ? bmp[col] : bself[col - DD];
#pragma unroll
    for (int m = 0; m < 4; ++m) {
#pragma unroll
      for (int q = 0; q < 4; ++q) {
        const int row = mb + wr + m * 16 + lg * 4 + q;
        float v = acc[m][n][q];
        if (mode == 0) {
          const float* sp = sbuf + (size_t)row * 8;
          float bias = 0.f;
#pragma unroll
          for (int r = 0; r < 8; ++r) bias += sp[r] * bcol[r];
          v = fmaxf(v + bias, 0.f);
        } else {
          v += bb;
        }
        o_bf[(size_t)row * ostride + col] = f2bf(v);
      }
    }
  }
}

// ---- MP aggregation + self + relu ----
__global__ __launch_bounds__(192) void k_edge_mp(
    const u16* __restrict__ lin2, const int* __restrict__ rp,
    const int* __restrict__ epack, u16* __restrict__ Hout) {
  const int i = blockIdx.x, t = threadIdx.x;
  const int e0 = rp[i], e1 = rp[i + 1];
  float ax = 0.f, ay = 0.f;
  for (int e = e0; e < e1; ++e) {
    const int src = epack[e] & 0xffff;
    const float2 hv = up2(*(const u32*)(lin2 + (size_t)src * LN2 + 2 * t));
    ax += hv.x; ay += hv.y;
  }
  const float2 sl = up2(*(const u32*)(lin2 + (size_t)i * LN2 + DD + 2 * t));
  ax = fmaxf(ax + sl.x, 0.f);
  ay = fmaxf(ay + sl.y, 0.f);
  *(u32*)(Hout + (size_t)i * DD + 2 * t) = pk2(ax, ay);
}

// ---- mean over 256 nodes per graph ----
__global__ __launch_bounds__(192) void k_mean(const u16* __restrict__ H,
                                              float* __restrict__ out) {
  const int g = blockIdx.x, t = threadIdx.x;
  float ax = 0.f, ay = 0.f;
  const u16* base = H + (size_t)g * 256 * DD;
  for (int j = 0; j < 256; ++j) {
    const float2 hv = up2(*(const u32*)(base + (size_t)j * DD + 2 * t));
    ax += hv.x; ay += hv.y;
  }
  out[g * DD + 2 * t]     = ax * (1.f / 256.f);
  out[g * DD + 2 * t + 1] = ay * (1.f / 256.f);
}

extern "C" void kernel_launch(void* const* d_in, const int* in_sizes, int n_in,
                              void* d_out, int out_size, void* d_ws, size_t ws_size,
                              hipStream_t stream) {
  const float* x     = (const float*)d_in[0];
  const int*   ei    = (const int*)d_in[1];
  const int*   ety   = (const int*)d_in[2];
  const float* Wrel  = (const float*)d_in[4];
  const float* brel  = (const float*)d_in[5];
  const float* ncs   = (const float*)d_in[6];
  const float* Wmp   = (const float*)d_in[7];
  const float* bmp   = (const float*)d_in[8];
  const float* Wself = (const float*)d_in[9];
  const float* bself = (const float*)d_in[10];
  float* out = (float*)d_out;
  (void)in_sizes; (void)n_in; (void)out_size;

  char* ws = (char*)d_ws;
  size_t off = 0;
  auto alloc = [&](size_t bytes) {
    void* p = ws + off;
    off = (off + bytes + 255) & ~(size_t)255;
    return p;
  };
  float* invn  = (float*)alloc((size_t)NN * 4);
  int*   rp    = (int*)alloc(((size_t)NN + 1) * 4);
  int*   cur   = (int*)alloc((size_t)NN * 4);
  float* sbuf  = (float*)alloc((size_t)NN * 8 * 4);
  float* we    = (float*)alloc((size_t)EE * 4);
  int*   epack = (int*)alloc((size_t)EE * 4);
  float* wsort = (float*)alloc((size_t)EE * 4);
  u16*   WcatT = (u16*)alloc((size_t)DD * KREL * 2);
  u16*   WmsT  = (u16*)alloc((size_t)LN2 * DD * 2);
  u16*   H     = (u16*)alloc((size_t)NN * DD * 2);
  u16*   H2    = (u16*)alloc((size_t)NN * DD * 2);
  u16*   lin2  = (u16*)alloc((size_t)NN * LN2 * 2);
  size_t remain = (ws_size > off) ? (ws_size - off) : 0;
  int C = NN;
  while (C > 1024 && (size_t)C * KREL * 2 > remain) C >>= 1;
  u16* agg = (u16*)(ws + off);

  k_invnorm<<<NN / 4, 256, 0, stream>>>(x, invn, H, cur);
  k_prepW<<<(DD * KREL + LN2 * DD) / 256, 256, 0, stream>>>(Wrel, Wmp, Wself, WcatT, WmsT);
  k_cos<<<EE / 4, 256, 0, stream>>>(H, invn, ei, ety, ncs, we, cur);
  k_scan<<<1, 1024, 0, stream>>>(cur, rp, cur);
  k_scatter<<<EE / 256, 256, 0, stream>>>(ei, ety, we, cur, epack, wsort);

  for (int layer = 0; layer < 2; ++layer) {
    for (int c0 = 0; c0 < NN; c0 += C) {
      k_edge_rel<<<C, 192, 0, stream>>>(H, rp, epack, wsort, agg, sbuf, c0);
      k_gemm<<<dim3(3, C / 128), 256, 0, stream>>>(agg, WcatT, KREL, 0,
                                                   H2 + (size_t)c0 * DD, DD,
                                                   sbuf + (size_t)c0 * 8, brel, nullptr, nullptr);
    }
    k_gemm<<<dim3(6, NN / 128), 256, 0, stream>>>(H2, WmsT, DD, 1,
                                                  lin2, LN2, nullptr, nullptr, bmp, bself);
    k_edge_mp<<<NN, 192, 0, stream>>>(lin2, rp, epack, H);
  }
  k_mean<<<NGR, 192, 0, stream>>>(H, out);
}